// Round 1
// baseline (293.498 us; speedup 1.0000x reference)
//
#include <hip/hip_runtime.h>
#include <hip/hip_bf16.h>
#include <cstdint>

typedef __bf16 bf16_t;
typedef __bf16 bf16x8 __attribute__((ext_vector_type(8)));
typedef __bf16 bf16x4 __attribute__((ext_vector_type(4)));
typedef float  f32x4  __attribute__((ext_vector_type(4)));

static constexpr int Bb = 2;
static constexpr int Tt = 2048;
static constexpr int Dd = 1024;
static constexpr int Hh = 16;
static constexpr int HD = 64;

#define LOG2E 1.4426950408889634f

// ---------------- fp32 -> bf16 elementwise (8 elems/thread) ----------------
__global__ __launch_bounds__(256) void cvt_bf16_kernel(const float* __restrict__ in,
                                                       bf16_t* __restrict__ out, int n) {
    int i = (blockIdx.x * 256 + threadIdx.x) * 8;
    if (i >= n) return;
    float4 v0 = *(const float4*)(in + i);
    float4 v1 = *(const float4*)(in + i + 4);
    bf16x8 o;
    o[0] = (bf16_t)v0.x; o[1] = (bf16_t)v0.y; o[2] = (bf16_t)v0.z; o[3] = (bf16_t)v0.w;
    o[4] = (bf16_t)v1.x; o[5] = (bf16_t)v1.y; o[6] = (bf16_t)v1.z; o[7] = (bf16_t)v1.w;
    *(bf16x8*)(out + i) = o;
}

// ------------- transpose + convert: in[R][C] fp32 -> out[C][R] bf16 -------------
__global__ __launch_bounds__(256) void transpose_cvt(const float* __restrict__ in,
                                                     bf16_t* __restrict__ out,
                                                     int R, int C) {
    __shared__ bf16_t tile[64][72];
    int tr = blockIdx.y * 64, tc = blockIdx.x * 64;
    int t = threadIdx.x;
    int r = t >> 4;          // 0..15
    int c4 = (t & 15) * 4;   // 0..60
#pragma unroll
    for (int rr = 0; rr < 4; ++rr) {
        int row = r + rr * 16;
        float4 v = *(const float4*)(in + (size_t)(tr + row) * C + tc + c4);
        tile[c4 + 0][row] = (bf16_t)v.x;
        tile[c4 + 1][row] = (bf16_t)v.y;
        tile[c4 + 2][row] = (bf16_t)v.z;
        tile[c4 + 3][row] = (bf16_t)v.w;
    }
    __syncthreads();
#pragma unroll
    for (int rr = 0; rr < 4; ++rr) {
        int oc = r + rr * 16;
        bf16x4 o;
        o[0] = tile[oc][c4 + 0];
        o[1] = tile[oc][c4 + 1];
        o[2] = tile[oc][c4 + 2];
        o[3] = tile[oc][c4 + 3];
        *(bf16x4*)(out + (size_t)(tc + oc) * R + tr + c4) = o;
    }
}

// ------------- GEMM: C[M][N] = A[M][K] * Bt[N][K]^T + bias -------------
// MODE 0: write fp32 C row-major.  MODE 1: split-scatter qkv into q/k/v bf16 buffers.
template <int MODE>
__global__ __launch_bounds__(256) void gemm_bt(
    const bf16_t* __restrict__ A, const bf16_t* __restrict__ Bt,
    const float* __restrict__ bias, float* __restrict__ Cout,
    bf16_t* __restrict__ qb_, bf16_t* __restrict__ kb_, bf16_t* __restrict__ vb_,
    int M, int N, int K) {
    __shared__ bf16_t As[128][40];
    __shared__ bf16_t Bs[128][40];
    int t = threadIdx.x;
    int wave = t >> 6, lane = t & 63;
    int l15 = lane & 15, quad = lane >> 4;
    int wm = wave & 1, wn = wave >> 1;
    int m0 = blockIdx.y * 128, n0 = blockIdx.x * 128;
    int srow = t >> 1, sk0 = (t & 1) * 16;

    f32x4 acc[4][4];
#pragma unroll
    for (int mi = 0; mi < 4; ++mi)
#pragma unroll
        for (int ni = 0; ni < 4; ++ni) acc[mi][ni] = (f32x4){0.f, 0.f, 0.f, 0.f};

    for (int kk = 0; kk < K; kk += 32) {
        __syncthreads();
        const bf16_t* ag = A + (size_t)(m0 + srow) * K + kk + sk0;
        *(bf16x8*)(&As[srow][sk0])     = *(const bf16x8*)(ag);
        *(bf16x8*)(&As[srow][sk0 + 8]) = *(const bf16x8*)(ag + 8);
        const bf16_t* bg = Bt + (size_t)(n0 + srow) * K + kk + sk0;
        *(bf16x8*)(&Bs[srow][sk0])     = *(const bf16x8*)(bg);
        *(bf16x8*)(&Bs[srow][sk0 + 8]) = *(const bf16x8*)(bg + 8);
        __syncthreads();
        bf16x8 af[4], bf[4];
#pragma unroll
        for (int mi = 0; mi < 4; ++mi)
            af[mi] = *(const bf16x8*)(&As[wm * 64 + mi * 16 + l15][quad * 8]);
#pragma unroll
        for (int ni = 0; ni < 4; ++ni)
            bf[ni] = *(const bf16x8*)(&Bs[wn * 64 + ni * 16 + l15][quad * 8]);
#pragma unroll
        for (int mi = 0; mi < 4; ++mi)
#pragma unroll
            for (int ni = 0; ni < 4; ++ni)
                acc[mi][ni] = __builtin_amdgcn_mfma_f32_16x16x32_bf16(af[mi], bf[ni], acc[mi][ni], 0, 0, 0);
    }

#pragma unroll
    for (int ni = 0; ni < 4; ++ni) {
        int col = n0 + wn * 64 + ni * 16 + l15;
        float bv = bias[col];
#pragma unroll
        for (int mi = 0; mi < 4; ++mi) {
#pragma unroll
            for (int r = 0; r < 4; ++r) {
                int row = m0 + wm * 64 + mi * 16 + quad * 4 + r;
                float v = acc[mi][ni][r] + bv;
                if (MODE == 0) {
                    Cout[(size_t)row * N + col] = v;
                } else {
                    int sec = col >> 10;
                    int hh = (col >> 6) & 15;
                    int dd = col & 63;
                    int bb = row >> 11;
                    int tt = row & (Tt - 1);
                    if (sec == 2) {
                        vb_[(((size_t)(bb * Hh + hh)) * HD + dd) * Tt + tt] = (bf16_t)v;
                    } else {
                        size_t idx = (((size_t)(bb * Hh + hh)) * Tt + tt) * HD + dd;
                        if (sec == 0) qb_[idx] = (bf16_t)v;
                        else          kb_[idx] = (bf16_t)v;
                    }
                }
            }
        }
    }
}

// ------------- flash attention, causal -------------
// q/k: [BH][T][64] bf16, v: [BH][64][T] bf16, out: [B][T][H][64] bf16
__global__ __launch_bounds__(256) void attn_kernel(
    const bf16_t* __restrict__ qb, const bf16_t* __restrict__ kb,
    const bf16_t* __restrict__ vb, bf16_t* __restrict__ ob) {
    __shared__ bf16_t Ks[64][72];
    __shared__ bf16_t Vs[64][72];
    __shared__ bf16_t Ps[4][16][72];
    int t = threadIdx.x;
    int wave = t >> 6, lane = t & 63;
    int l15 = lane & 15, quad = lane >> 4;
    int qt = (int)gridDim.x - 1 - (int)blockIdx.x;  // big tiles first
    int bh = blockIdx.y;
    int b = bh >> 4, h = bh & 15;
    int qr0 = qt * 64 + wave * 16;
    const bf16_t* qbase = qb + (size_t)bh * Tt * HD;
    const bf16_t* kbase = kb + (size_t)bh * Tt * HD;
    const bf16_t* vbase = vb + (size_t)bh * HD * Tt;

    bf16x8 qf[2];
    qf[0] = *(const bf16x8*)(qbase + (size_t)(qr0 + l15) * HD + quad * 8);
    qf[1] = *(const bf16x8*)(qbase + (size_t)(qr0 + l15) * HD + 32 + quad * 8);

    f32x4 o[4];
#pragma unroll
    for (int g = 0; g < 4; ++g) o[g] = (f32x4){0.f, 0.f, 0.f, 0.f};
    float mrow[4], lrow[4];
    int q_abs[4];
#pragma unroll
    for (int r = 0; r < 4; ++r) {
        mrow[r] = -1e30f;
        lrow[r] = 0.f;
        q_abs[r] = qt * 64 + wave * 16 + quad * 4 + r;
    }

    int si = t >> 2;          // 0..63
    int sj = (t & 3) * 16;    // 0,16,32,48

    int nkt = qt + 1;
    for (int it = 0; it < nkt; ++it) {
        int kt0 = it * 64;
        __syncthreads();
        *(bf16x8*)(&Ks[si][sj])     = *(const bf16x8*)(kbase + (size_t)(kt0 + si) * HD + sj);
        *(bf16x8*)(&Ks[si][sj + 8]) = *(const bf16x8*)(kbase + (size_t)(kt0 + si) * HD + sj + 8);
        *(bf16x8*)(&Vs[si][sj])     = *(const bf16x8*)(vbase + (size_t)si * Tt + kt0 + sj);
        *(bf16x8*)(&Vs[si][sj + 8]) = *(const bf16x8*)(vbase + (size_t)si * Tt + kt0 + sj + 8);
        __syncthreads();

        f32x4 s[4];
#pragma unroll
        for (int g = 0; g < 4; ++g) {
            s[g] = (f32x4){0.f, 0.f, 0.f, 0.f};
            bf16x8 kf0 = *(const bf16x8*)(&Ks[g * 16 + l15][quad * 8]);
            bf16x8 kf1 = *(const bf16x8*)(&Ks[g * 16 + l15][32 + quad * 8]);
            s[g] = __builtin_amdgcn_mfma_f32_16x16x32_bf16(qf[0], kf0, s[g], 0, 0, 0);
            s[g] = __builtin_amdgcn_mfma_f32_16x16x32_bf16(qf[1], kf1, s[g], 0, 0, 0);
        }

        float mt[4] = {-1e30f, -1e30f, -1e30f, -1e30f};
#pragma unroll
        for (int g = 0; g < 4; ++g) {
#pragma unroll
            for (int r = 0; r < 4; ++r) {
                int k_abs = kt0 + g * 16 + l15;
                float sv = s[g][r] * 0.125f;
                sv = (k_abs > q_abs[r]) ? -1e30f : sv;
                s[g][r] = sv;
                mt[r] = fmaxf(mt[r], sv);
            }
        }
#pragma unroll
        for (int off = 1; off < 16; off <<= 1)
#pragma unroll
            for (int r = 0; r < 4; ++r) mt[r] = fmaxf(mt[r], __shfl_xor(mt[r], off, 64));

        float alpha[4];
#pragma unroll
        for (int r = 0; r < 4; ++r) {
            float mnew = fmaxf(mrow[r], mt[r]);
            alpha[r] = exp2f((mrow[r] - mnew) * LOG2E);
            mrow[r] = mnew;
        }

        float rs[4] = {0.f, 0.f, 0.f, 0.f};
#pragma unroll
        for (int g = 0; g < 4; ++g) {
#pragma unroll
            for (int r = 0; r < 4; ++r) {
                float p = exp2f((s[g][r] - mrow[r]) * LOG2E);
                rs[r] += p;
                Ps[wave][quad * 4 + r][g * 16 + l15] = (bf16_t)p;
            }
        }
#pragma unroll
        for (int off = 1; off < 16; off <<= 1)
#pragma unroll
            for (int r = 0; r < 4; ++r) rs[r] += __shfl_xor(rs[r], off, 64);
#pragma unroll
        for (int r = 0; r < 4; ++r) lrow[r] = lrow[r] * alpha[r] + rs[r];
#pragma unroll
        for (int g = 0; g < 4; ++g)
#pragma unroll
            for (int r = 0; r < 4; ++r) o[g][r] *= alpha[r];

#pragma unroll
        for (int c = 0; c < 2; ++c) {
            bf16x8 pf = *(const bf16x8*)(&Ps[wave][l15][c * 32 + quad * 8]);
#pragma unroll
            for (int g = 0; g < 4; ++g) {
                bf16x8 vf = *(const bf16x8*)(&Vs[g * 16 + l15][c * 32 + quad * 8]);
                o[g] = __builtin_amdgcn_mfma_f32_16x16x32_bf16(pf, vf, o[g], 0, 0, 0);
            }
        }
    }

#pragma unroll
    for (int r = 0; r < 4; ++r) {
        float inv = 1.0f / lrow[r];
        int tt = qr0 + quad * 4 + r;
#pragma unroll
        for (int g = 0; g < 4; ++g) {
            int dv = g * 16 + l15;
            ob[(((size_t)(b * Tt + tt)) * Hh + h) * HD + dv] = (bf16_t)(o[g][r] * inv);
        }
    }
}

extern "C" void kernel_launch(void* const* d_in, const int* in_sizes, int n_in,
                              void* d_out, int out_size, void* d_ws, size_t ws_size,
                              hipStream_t stream) {
    const float* x      = (const float*)d_in[0];
    const float* W_kqv  = (const float*)d_in[1];
    const float* b_kqv  = (const float*)d_in[2];
    const float* W_proj = (const float*)d_in[3];
    const float* b_proj = (const float*)d_in[4];
    float* out = (float*)d_out;
    char* ws = (char*)d_ws;
    const size_t MB = 1ull << 20;
    bf16_t* x_bf   = (bf16_t*)(ws + 0 * MB);   // 8 MB  [4096][1024]
    bf16_t* wkqvt  = (bf16_t*)(ws + 8 * MB);   // 6 MB  [3072][1024]
    bf16_t* wprojt = (bf16_t*)(ws + 14 * MB);  // 2 MB  [1024][1024]
    bf16_t* qb     = (bf16_t*)(ws + 16 * MB);  // 8 MB  [32][2048][64]
    bf16_t* kb     = (bf16_t*)(ws + 24 * MB);  // 8 MB  [32][2048][64]
    bf16_t* vb     = (bf16_t*)(ws + 32 * MB);  // 8 MB  [32][64][2048]
    bf16_t* ab     = (bf16_t*)(ws + 40 * MB);  // 8 MB  [2][2048][16][64]

    cvt_bf16_kernel<<<(Bb * Tt * Dd) / (256 * 8), 256, 0, stream>>>(x, x_bf, Bb * Tt * Dd);
    transpose_cvt<<<dim3(3 * Dd / 64, Dd / 64), 256, 0, stream>>>(W_kqv, wkqvt, Dd, 3 * Dd);
    transpose_cvt<<<dim3(Dd / 64, Dd / 64), 256, 0, stream>>>(W_proj, wprojt, Dd, Dd);
    gemm_bt<1><<<dim3(3 * Dd / 128, Bb * Tt / 128), 256, 0, stream>>>(
        x_bf, wkqvt, b_kqv, nullptr, qb, kb, vb, Bb * Tt, 3 * Dd, Dd);
    attn_kernel<<<dim3(Tt / 64, Bb * Hh), 256, 0, stream>>>(qb, kb, vb, ab);
    gemm_bt<0><<<dim3(Dd / 128, Bb * Tt / 128), 256, 0, stream>>>(
        ab, wprojt, b_proj, out, nullptr, nullptr, nullptr, Bb * Tt, Dd, Dd);
}

// Round 2
// 226.670 us; speedup vs baseline: 1.2948x; 1.2948x over previous
//
#include <hip/hip_runtime.h>
#include <hip/hip_bf16.h>
#include <cstdint>

typedef __bf16 bf16_t;
typedef __bf16 bf16x8 __attribute__((ext_vector_type(8)));
typedef __bf16 bf16x4 __attribute__((ext_vector_type(4)));
typedef float  f32x4  __attribute__((ext_vector_type(4)));

static constexpr int Bb = 2;
static constexpr int Tt = 2048;
static constexpr int Dd = 1024;
static constexpr int Hh = 16;
static constexpr int HD = 64;

// 0.125 (1/sqrt(64)) * log2(e), folded into q at the QKV-GEMM epilogue so the
// attention softmax is pure exp2 with no per-element scale.
#define QSCALE 0.18033688011112042f

// ---------------- fp32 -> bf16 elementwise (8 elems/thread) ----------------
__global__ __launch_bounds__(256) void cvt_bf16_kernel(const float* __restrict__ in,
                                                       bf16_t* __restrict__ out, int n) {
    int i = (blockIdx.x * 256 + threadIdx.x) * 8;
    if (i >= n) return;
    float4 v0 = *(const float4*)(in + i);
    float4 v1 = *(const float4*)(in + i + 4);
    bf16x8 o;
    o[0] = (bf16_t)v0.x; o[1] = (bf16_t)v0.y; o[2] = (bf16_t)v0.z; o[3] = (bf16_t)v0.w;
    o[4] = (bf16_t)v1.x; o[5] = (bf16_t)v1.y; o[6] = (bf16_t)v1.z; o[7] = (bf16_t)v1.w;
    *(bf16x8*)(out + i) = o;
}

// ------------- transpose + convert: in[R][C] fp32 -> out[C][R] bf16 -------------
__global__ __launch_bounds__(256) void transpose_cvt(const float* __restrict__ in,
                                                     bf16_t* __restrict__ out,
                                                     int R, int C) {
    __shared__ bf16_t tile[64][72];
    int tr = blockIdx.y * 64, tc = blockIdx.x * 64;
    int t = threadIdx.x;
    int r = t >> 4;          // 0..15
    int c4 = (t & 15) * 4;   // 0..60
#pragma unroll
    for (int rr = 0; rr < 4; ++rr) {
        int row = r + rr * 16;
        float4 v = *(const float4*)(in + (size_t)(tr + row) * C + tc + c4);
        tile[c4 + 0][row] = (bf16_t)v.x;
        tile[c4 + 1][row] = (bf16_t)v.y;
        tile[c4 + 2][row] = (bf16_t)v.z;
        tile[c4 + 3][row] = (bf16_t)v.w;
    }
    __syncthreads();
#pragma unroll
    for (int rr = 0; rr < 4; ++rr) {
        int oc = r + rr * 16;
        bf16x4 o;
        o[0] = tile[oc][c4 + 0];
        o[1] = tile[oc][c4 + 1];
        o[2] = tile[oc][c4 + 2];
        o[3] = tile[oc][c4 + 3];
        *(bf16x4*)(out + (size_t)(tc + oc) * R + tr + c4) = o;
    }
}

// ------------- GEMM: C[M][N] = A[M][K] * Bt[N][K]^T + bias -------------
// MODE 0: write fp32 C row-major.  MODE 1: split-scatter qkv into q/k/v bf16 buffers.
template <int MODE>
__global__ __launch_bounds__(256) void gemm_bt(
    const bf16_t* __restrict__ A, const bf16_t* __restrict__ Bt,
    const float* __restrict__ bias, float* __restrict__ Cout,
    bf16_t* __restrict__ qb_, bf16_t* __restrict__ kb_, bf16_t* __restrict__ vb_,
    int M, int N, int K) {
    __shared__ bf16_t As[128][40];
    __shared__ bf16_t Bs[128][40];
    int t = threadIdx.x;
    int wave = t >> 6, lane = t & 63;
    int l15 = lane & 15, quad = lane >> 4;
    int wm = wave & 1, wn = wave >> 1;
    int m0 = blockIdx.y * 128, n0 = blockIdx.x * 128;
    int srow = t >> 1, sk0 = (t & 1) * 16;

    f32x4 acc[4][4];
#pragma unroll
    for (int mi = 0; mi < 4; ++mi)
#pragma unroll
        for (int ni = 0; ni < 4; ++ni) acc[mi][ni] = (f32x4){0.f, 0.f, 0.f, 0.f};

    for (int kk = 0; kk < K; kk += 32) {
        __syncthreads();
        const bf16_t* ag = A + (size_t)(m0 + srow) * K + kk + sk0;
        *(bf16x8*)(&As[srow][sk0])     = *(const bf16x8*)(ag);
        *(bf16x8*)(&As[srow][sk0 + 8]) = *(const bf16x8*)(ag + 8);
        const bf16_t* bg = Bt + (size_t)(n0 + srow) * K + kk + sk0;
        *(bf16x8*)(&Bs[srow][sk0])     = *(const bf16x8*)(bg);
        *(bf16x8*)(&Bs[srow][sk0 + 8]) = *(const bf16x8*)(bg + 8);
        __syncthreads();
        bf16x8 af[4], bf[4];
#pragma unroll
        for (int mi = 0; mi < 4; ++mi)
            af[mi] = *(const bf16x8*)(&As[wm * 64 + mi * 16 + l15][quad * 8]);
#pragma unroll
        for (int ni = 0; ni < 4; ++ni)
            bf[ni] = *(const bf16x8*)(&Bs[wn * 64 + ni * 16 + l15][quad * 8]);
#pragma unroll
        for (int mi = 0; mi < 4; ++mi)
#pragma unroll
            for (int ni = 0; ni < 4; ++ni)
                acc[mi][ni] = __builtin_amdgcn_mfma_f32_16x16x32_bf16(af[mi], bf[ni], acc[mi][ni], 0, 0, 0);
    }

#pragma unroll
    for (int ni = 0; ni < 4; ++ni) {
        int col = n0 + wn * 64 + ni * 16 + l15;
        float bv = bias[col];
#pragma unroll
        for (int mi = 0; mi < 4; ++mi) {
#pragma unroll
            for (int r = 0; r < 4; ++r) {
                int row = m0 + wm * 64 + mi * 16 + quad * 4 + r;
                float v = acc[mi][ni][r] + bv;
                if (MODE == 0) {
                    Cout[(size_t)row * N + col] = v;
                } else {
                    int sec = col >> 10;
                    int hh = (col >> 6) & 15;
                    int dd = col & 63;
                    int bb = row >> 11;
                    int tt = row & (Tt - 1);
                    if (sec == 2) {
                        vb_[(((size_t)(bb * Hh + hh)) * HD + dd) * Tt + tt] = (bf16_t)v;
                    } else {
                        size_t idx = (((size_t)(bb * Hh + hh)) * Tt + tt) * HD + dd;
                        if (sec == 0) qb_[idx] = (bf16_t)(v * QSCALE);
                        else          kb_[idx] = (bf16_t)v;
                    }
                }
            }
        }
    }
}

// ------------- flash attention, causal -------------
// q/k: [BH][T][64] bf16 (q pre-scaled by QSCALE), v: [BH][64][T] bf16 (V^T),
// out ab: [B][T][H*64] bf16.
// Block: 512 threads = 8 waves; Q-tile 128 (16 q-rows/wave); K-tile 64.
// Score MFMA computes S^T (A=K, B=Q) so col=l15=q -> softmax state is
// per-lane scalar, reductions are in-register + 2 shuffles.
// PV computes O^T (A=V^T, B=P) so O col=l15=q matches softmax state.
__global__ __launch_bounds__(512, 4) void attn_kernel(
    const bf16_t* __restrict__ qb, const bf16_t* __restrict__ kb,
    const bf16_t* __restrict__ vb, bf16_t* __restrict__ ab) {
    __shared__ bf16_t Ks[64][72];       // [k][d]
    __shared__ bf16_t Vs[64][72];       // [d][k]  (V^T tile)
    __shared__ bf16_t Ps[8][16][72];    // per-wave [q][k]
    int t = threadIdx.x;
    int wave = t >> 6, lane = t & 63;
    int l15 = lane & 15, quad = lane >> 4;
    int bh = blockIdx.y;
    int x = blockIdx.x;
    // pair heavy (qt=15) with light (qt=0) blocks for CU load balance
    int qt = (bh < 16) ? x : (15 - x);
    int b = bh >> 4, h = bh & 15;
    int qbase = qt * 128 + wave * 16;   // this wave's first q-row
    int q = qbase + l15;                // this lane's q-row (softmax state owner)
    const bf16_t* qptr = qb + (size_t)bh * Tt * HD;
    const bf16_t* kptr = kb + (size_t)bh * Tt * HD;
    const bf16_t* vptr = vb + (size_t)bh * HD * Tt;

    // Q fragment as MFMA B-operand: row n=l15 -> q, k'=quad*8+j -> d
    bf16x8 qf[2];
    qf[0] = *(const bf16x8*)(qptr + (size_t)q * HD + quad * 8);
    qf[1] = *(const bf16x8*)(qptr + (size_t)q * HD + 32 + quad * 8);

    f32x4 o[4];  // O^T: row d = g*16+quad*4+r, col q = l15
#pragma unroll
    for (int g = 0; g < 4; ++g) o[g] = (f32x4){0.f, 0.f, 0.f, 0.f};
    float mrow = -1e30f, lrow = 0.f;

    int srow = t >> 3;          // 0..63
    int scol = (t & 7) * 8;     // 0..56
    int qmax_w = qbase + 15;

    int nkt = 2 * qt + 2;
    for (int it = 0; it < nkt; ++it) {
        int kt0 = it * 64;
        __syncthreads();
        *(bf16x8*)(&Ks[srow][scol]) = *(const bf16x8*)(kptr + (size_t)(kt0 + srow) * HD + scol);
        *(bf16x8*)(&Vs[srow][scol]) = *(const bf16x8*)(vptr + (size_t)srow * Tt + kt0 + scol);
        __syncthreads();
        if (kt0 > qmax_w) continue;  // wave-uniform: past this wave's diagonal

        // S^T = K · Q^T : row = k = g*16+quad*4+r, col = q = l15
        f32x4 s[4];
#pragma unroll
        for (int g = 0; g < 4; ++g) {
            s[g] = (f32x4){0.f, 0.f, 0.f, 0.f};
            bf16x8 kf0 = *(const bf16x8*)(&Ks[g * 16 + l15][quad * 8]);
            bf16x8 kf1 = *(const bf16x8*)(&Ks[g * 16 + l15][32 + quad * 8]);
            s[g] = __builtin_amdgcn_mfma_f32_16x16x32_bf16(kf0, qf[0], s[g], 0, 0, 0);
            s[g] = __builtin_amdgcn_mfma_f32_16x16x32_bf16(kf1, qf[1], s[g], 0, 0, 0);
        }

        // causal mask: exactly one tile per wave straddles its diagonal
        if (kt0 + 63 > qbase) {
#pragma unroll
            for (int g = 0; g < 4; ++g)
#pragma unroll
                for (int r = 0; r < 4; ++r) {
                    int k_abs = kt0 + g * 16 + quad * 4 + r;
                    s[g][r] = (k_abs > q) ? -1e30f : s[g][r];
                }
        }

        // row max: 16 in-register values + 2 shuffles across quads
        float mloc = -1e30f;
#pragma unroll
        for (int g = 0; g < 4; ++g)
            mloc = fmaxf(mloc, fmaxf(fmaxf(s[g][0], s[g][1]), fmaxf(s[g][2], s[g][3])));
        mloc = fmaxf(mloc, __shfl_xor(mloc, 16));
        mloc = fmaxf(mloc, __shfl_xor(mloc, 32));
        float mnew = fmaxf(mrow, mloc);
        float alpha = exp2f(mrow - mnew);
        mrow = mnew;

        // p = exp2(s - m), accumulate row sum, write P^T -> Ps[q][k] (bf16x4)
        float rs = 0.f;
#pragma unroll
        for (int g = 0; g < 4; ++g) {
            float p0 = exp2f(s[g][0] - mnew);
            float p1 = exp2f(s[g][1] - mnew);
            float p2 = exp2f(s[g][2] - mnew);
            float p3 = exp2f(s[g][3] - mnew);
            rs += (p0 + p1) + (p2 + p3);
            bf16x4 pk;
            pk[0] = (bf16_t)p0; pk[1] = (bf16_t)p1; pk[2] = (bf16_t)p2; pk[3] = (bf16_t)p3;
            *(bf16x4*)(&Ps[wave][l15][g * 16 + quad * 4]) = pk;
        }
        rs += __shfl_xor(rs, 16);
        rs += __shfl_xor(rs, 32);
        lrow = lrow * alpha + rs;

#pragma unroll
        for (int g = 0; g < 4; ++g)
#pragma unroll
            for (int r = 0; r < 4; ++r) o[g][r] *= alpha;

        // O^T += V^T · P^T : A = Vs rows d, B = Ps rows q
#pragma unroll
        for (int kc = 0; kc < 2; ++kc) {
            bf16x8 pf = *(const bf16x8*)(&Ps[wave][l15][kc * 32 + quad * 8]);
#pragma unroll
            for (int g = 0; g < 4; ++g) {
                bf16x8 vf = *(const bf16x8*)(&Vs[g * 16 + l15][kc * 32 + quad * 8]);
                o[g] = __builtin_amdgcn_mfma_f32_16x16x32_bf16(vf, pf, o[g], 0, 0, 0);
            }
        }
    }

    // epilogue: normalize, write ab[b][q][h*64+d], d = g*16+quad*4+r
    float inv = 1.0f / lrow;
    size_t obase = ((size_t)b * Tt + q) * Dd + h * 64;
#pragma unroll
    for (int g = 0; g < 4; ++g) {
        bf16x4 ov;
#pragma unroll
        for (int r = 0; r < 4; ++r) ov[r] = (bf16_t)(o[g][r] * inv);
        *(bf16x4*)(ab + obase + g * 16 + quad * 4) = ov;
    }
}

extern "C" void kernel_launch(void* const* d_in, const int* in_sizes, int n_in,
                              void* d_out, int out_size, void* d_ws, size_t ws_size,
                              hipStream_t stream) {
    const float* x      = (const float*)d_in[0];
    const float* W_kqv  = (const float*)d_in[1];
    const float* b_kqv  = (const float*)d_in[2];
    const float* W_proj = (const float*)d_in[3];
    const float* b_proj = (const float*)d_in[4];
    float* out = (float*)d_out;
    char* ws = (char*)d_ws;
    const size_t MB = 1ull << 20;
    bf16_t* x_bf   = (bf16_t*)(ws + 0 * MB);   // 8 MB  [4096][1024]
    bf16_t* wkqvt  = (bf16_t*)(ws + 8 * MB);   // 6 MB  [3072][1024]
    bf16_t* wprojt = (bf16_t*)(ws + 14 * MB);  // 2 MB  [1024][1024]
    bf16_t* qb     = (bf16_t*)(ws + 16 * MB);  // 8 MB  [32][2048][64]  (pre-scaled)
    bf16_t* kb     = (bf16_t*)(ws + 24 * MB);  // 8 MB  [32][2048][64]
    bf16_t* vb     = (bf16_t*)(ws + 32 * MB);  // 8 MB  [32][64][2048]  (V^T)
    bf16_t* ab     = (bf16_t*)(ws + 40 * MB);  // 8 MB  [2][2048][16*64]

    cvt_bf16_kernel<<<(Bb * Tt * Dd) / (256 * 8), 256, 0, stream>>>(x, x_bf, Bb * Tt * Dd);
    transpose_cvt<<<dim3(3 * Dd / 64, Dd / 64), 256, 0, stream>>>(W_kqv, wkqvt, Dd, 3 * Dd);
    transpose_cvt<<<dim3(Dd / 64, Dd / 64), 256, 0, stream>>>(W_proj, wprojt, Dd, Dd);
    gemm_bt<1><<<dim3(3 * Dd / 128, Bb * Tt / 128), 256, 0, stream>>>(
        x_bf, wkqvt, b_kqv, nullptr, qb, kb, vb, Bb * Tt, 3 * Dd, Dd);
    attn_kernel<<<dim3(16, Bb * Hh), 512, 0, stream>>>(qb, kb, vb, ab);
    gemm_bt<0><<<dim3(Dd / 128, Bb * Tt / 128), 256, 0, stream>>>(
        ab, wprojt, b_proj, out, nullptr, nullptr, nullptr, Bb * Tt, Dd, Dd);
}